// Round 13
// baseline (1087.900 us; speedup 1.0000x reference)
//
#include <hip/hip_runtime.h>
#include <math.h>
#include <stdint.h>

#define VOCAB 64
#define H 64
#define BB 256
#define LL 2048

typedef float v2f __attribute__((ext_vector_type(2)));

// 64-lane wave sum via DPP (row_shr 1/2/4/8, row_bcast15, row_bcast31), then
// broadcast total from lane 63. All VALU-pipe, no LDS latency.
__device__ __forceinline__ float wave_sum_dpp(float x) {
  int t;
  float r = x;
  t = __builtin_amdgcn_update_dpp(0, __float_as_int(r), 0x111, 0xf, 0xf, true); r += __int_as_float(t);
  t = __builtin_amdgcn_update_dpp(0, __float_as_int(r), 0x112, 0xf, 0xf, true); r += __int_as_float(t);
  t = __builtin_amdgcn_update_dpp(0, __float_as_int(r), 0x114, 0xf, 0xf, true); r += __int_as_float(t);
  t = __builtin_amdgcn_update_dpp(0, __float_as_int(r), 0x118, 0xf, 0xf, true); r += __int_as_float(t);
  t = __builtin_amdgcn_update_dpp(0, __float_as_int(r), 0x142, 0xf, 0xf, true); r += __int_as_float(t);
  t = __builtin_amdgcn_update_dpp(0, __float_as_int(r), 0x143, 0xf, 0xf, true); r += __int_as_float(t);
  return __int_as_float(__builtin_amdgcn_readlane(__float_as_int(r), 63));
}

// Phase 1: hidden depends only on the token id -> precompute 64 hidden vectors.
__global__ __launch_bounds__(64, 1) void encode_kernel(
    const float* __restrict__ embed, const float* __restrict__ W1,
    const float* __restrict__ b1, const float* __restrict__ W2,
    const float* __restrict__ b2, const float* __restrict__ gamma,
    const float* __restrict__ beta, float* __restrict__ table,
    float* __restrict__ kkg) {
  const int c = blockIdx.x;
  const int j = threadIdx.x;
  __shared__ float hs[H];
  __shared__ float zs[2 * H];
  const float h = embed[c * H + j];
  hs[j] = h;
  __syncthreads();
  float z0 = b1[j], z1 = b1[j + H];
#pragma unroll 8
  for (int i = 0; i < H; ++i) {
    const float hi = hs[i];
    z0 = fmaf(hi, W1[i * 2 * H + j], z0);
    z1 = fmaf(hi, W1[i * 2 * H + j + H], z1);
  }
  z0 = fmaxf(z0, 0.f);
  z1 = fmaxf(z1, 0.f);
  zs[j] = z0;
  zs[j + H] = z1;
  __syncthreads();
  float ff = b2[j];
#pragma unroll 8
  for (int m = 0; m < 2 * H; ++m) ff = fmaf(zs[m], W2[m * H + j], ff);
  const float x = h + ff;
  const float mu = wave_sum_dpp(x) * (1.f / 64.f);
  const float d = x - mu;
  const float var = wave_sum_dpp(d * d) * (1.f / 64.f);
  const float y = d * (1.f / sqrtf(var + 1e-5f)) * gamma[j] + beta[j];
  table[c * H + j] = y;
  const float s2 = wave_sum_dpp(y * y);
  if (j == 0) kkg[c] = s2;
}

// Phase 2+3: per-batch sequential scan. One block = one wave = one batch.
// Lane i owns row M[i][:]. KEY: all per-step addresses come from REGISTERS:
//  - tokens: whole stream packed 4/byte into 8 VGPRs, extracted by readlane
//    (index s>>2 is uniform; chunk register is always tokv[0] via rotation)
//  - kk: one VGPR (kkg distributed by lane), fetched by readlane(kkv, c)
// so the 33 LDS loads per step (two rows + sc) issue at the top of the
// single-basic-block body and their latency hides under the ~125-cycle gate
// chain. No loads are carried across iterations -> nothing to fold/sink.
// Arithmetic order identical to all passing rounds (bit-exact).
__global__ __launch_bounds__(64, 1) void scan_kernel(
    const int* __restrict__ seq, const float* __restrict__ table,
    const float* __restrict__ kkg, const float* __restrict__ Wr,
    const float* __restrict__ br, const float* __restrict__ Wo,
    const float* __restrict__ bo, float* __restrict__ out,
    float* __restrict__ counts) {
  const int b = blockIdx.x;
  const int lane = threadIdx.x;
  __shared__ float T[H * VOCAB];   // 16 KB: table, row c = key vector for token c
  __shared__ float xv[H];

  {
    const float4* src = (const float4*)table;
    float4* dst = (float4*)T;
#pragma unroll
    for (int q = 0; q < 16; ++q) dst[q * 64 + lane] = src[q * 64 + lane];
  }
  const float kkv = kkg[lane];     // k.k of vocab entry `lane`, one VGPR
  int tokv[8];                     // 2048 tokens, 4 per byte-packed reg/lane
  {
    const int4* s4 = (const int4*)(seq + (long)b * LL);
#pragma unroll
    for (int q = 0; q < 8; ++q) {
      const int4 w = s4[q * 64 + lane];
      tokv[q] = w.x | (w.y << 8) | (w.z << 16) | (w.w << 24);  // tokens < 64
    }
  }
  __syncthreads();

  v2f M2[32];
#pragma unroll
  for (int r = 0; r < 32; ++r) M2[r] = (v2f){0.f, 0.f};
  float wcount = 0.f;
  v2f vpA = (v2f){0.f, 0.f}, vpB = (v2f){0.f, 0.f};  // M=0 -> vp(0)=0

  // token t = blk*256 + s; chunk register rotated so index is always tokv[0]
#define TOK0(S_) \
  ((__builtin_amdgcn_readlane(tokv[0], (S_) >> 2) >> (8 * ((S_) & 3))) & 63)

  for (int blk = 0; blk < 8; ++blk) {
    const int smax = (blk == 7) ? 255 : 256;   // t goes 0..2046 (2047 steps)
    for (int s = 0; s < smax; ++s) {
      const int c = TOK0(s);                   // c_t  (uniform, SGPR)
      const int s1 = s + 1;
      const int cnx = (s1 < 256) ? TOK0(s1)    // c_{t+1}; chunk-cross at 255
                                 : (__builtin_amdgcn_readlane(tokv[1], 0) & 63);
      const float kk = __int_as_float(
          __builtin_amdgcn_readlane(__float_as_int(kkv), c));
      const float sc = T[c * H + lane];        // k_t[lane]
      const float4* up = (const float4*)(T + c * H);    // update row k_t
      const float4* xp = (const float4*)(T + cnx * H);  // dot row k_{t+1}
      const float vp = (vpA.x + vpA.y) + (vpB.x + vpB.y);
      const float dv = sc - vp / (kk + 1e-6f); // true divide (matches ref)
      const float aa = dv * (2.f * vp + dv * kk);
      const float sg = wave_sum_dpp(aa);       // wave-uniform gate
      const float dvg = sg > 0.f ? dv : 0.f;   // branchless (fma(0,..)=id)
      wcount += sg > 0.f ? 1.f : 0.f;
      const v2f dv2 = (v2f){dvg, dvg};
      v2f nA = (v2f){0.f, 0.f}, nB = (v2f){0.f, 0.f};
#pragma unroll
      for (int q = 0; q < 16; ++q) {
        const float4 kv4 = up[q];
        const float4 kn4 = xp[q];
        const v2f kva = (v2f){kv4.x, kv4.y}, kvb = (v2f){kv4.z, kv4.w};
        const v2f kna = (v2f){kn4.x, kn4.y}, knb = (v2f){kn4.z, kn4.w};
        M2[2 * q]     = __builtin_elementwise_fma(dv2, kva, M2[2 * q]);
        M2[2 * q + 1] = __builtin_elementwise_fma(dv2, kvb, M2[2 * q + 1]);
        nA = __builtin_elementwise_fma(M2[2 * q],     kna, nA);
        nB = __builtin_elementwise_fma(M2[2 * q + 1], knb, nB);
      }
      vpA = nA; vpB = nB;
    }
#pragma unroll
    for (int i = 0; i < 7; ++i) tokv[i] = tokv[i + 1];  // constant-index shift
  }

  // The last fused dot used row toks[LL-1]: vp == ctx[lane] in the same
  // accumulation order as before.
  xv[lane] = (vpA.x + vpA.y) + (vpB.x + vpB.y);
  __syncthreads();
  float t1 = br[lane];
#pragma unroll 8
  for (int i = 0; i < H; ++i) t1 = fmaf(xv[i], Wr[i * H + lane], t1);
  __syncthreads();
  xv[lane] = t1;
  __syncthreads();
  float lg = bo[lane];
#pragma unroll 8
  for (int m = 0; m < H; ++m) lg = fmaf(xv[m], Wo[m * H + lane], lg);
  out[(long)b * H + lane] = lg;
  if (lane == 0) counts[b] = wcount;
}

__global__ __launch_bounds__(256, 1) void finalize_kernel(const float* __restrict__ counts,
                                                          float* __restrict__ out) {
  const int lane = threadIdx.x;  // 256 threads
  __shared__ float sbuf[BB];
  sbuf[lane] = counts[lane];
  __syncthreads();
  for (int off = BB / 2; off > 0; off >>= 1) {
    if (lane < off) sbuf[lane] += sbuf[lane + off];
    __syncthreads();
  }
  if (lane == 0) out[BB * H] = sbuf[0] / (float)(BB * (LL - 1));
}

extern "C" void kernel_launch(void* const* d_in, const int* in_sizes, int n_in,
                              void* d_out, int out_size, void* d_ws, size_t ws_size,
                              hipStream_t stream) {
  const int* seq      = (const int*)d_in[0];
  const float* embed  = (const float*)d_in[1];
  const float* W1     = (const float*)d_in[2];
  const float* b1     = (const float*)d_in[3];
  const float* W2     = (const float*)d_in[4];
  const float* b2     = (const float*)d_in[5];
  const float* gamma  = (const float*)d_in[6];
  const float* beta   = (const float*)d_in[7];
  const float* Wr     = (const float*)d_in[8];
  const float* br     = (const float*)d_in[9];
  const float* Wo     = (const float*)d_in[10];
  const float* bo     = (const float*)d_in[11];
  float* out = (float*)d_out;

  float* table  = (float*)d_ws;          // 64*64 f32
  float* kkg    = table + VOCAB * H;     // 64 f32
  float* counts = kkg + VOCAB;           // 256 f32

  encode_kernel<<<VOCAB, H, 0, stream>>>(embed, W1, b1, W2, b2, gamma, beta, table, kkg);
  scan_kernel<<<BB, H, 0, stream>>>(seq, table, kkg, Wr, br, Wo, bo, out, counts);
  finalize_kernel<<<1, BB, 0, stream>>>(counts, out);
}